// Round 3
// baseline (415.500 us; speedup 1.0000x reference)
//
#include <hip/hip_runtime.h>

#define NM 23        // 3*K - 1, K = 8

__device__ __forceinline__ float softplus_f(float v) {
  // stable: max(v,0) + log(1 + exp(-|v|))
  return fmaxf(v, 0.f) + __logf(1.f + __expf(-fabsf(v)));
}

// ---------------------------------------------------------------------------
// Kernel A: layers 1+2 (MADE-masked), 64 rows/block, 1024 threads (16 waves).
// Small register footprint (acc arrays of 4/2) -> no spill risk at 1024 thr.
// Writes h2 (B x 32) to workspace; zeroes the log-det region of out.
// ---------------------------------------------------------------------------
__global__ __launch_bounds__(1024, 8) void h2_kernel(
    const float* __restrict__ x,
    const float* __restrict__ W1, const float* __restrict__ b1,
    const float* __restrict__ W2, const float* __restrict__ b2,
    float* __restrict__ h2out, float* __restrict__ ld_out, int B) {
  __shared__ float xs[64][65];     // overlaid by h2s[64][33] after layer 2
  __shared__ float h1s[64][65];

  const int t = threadIdx.x;
  const int b0 = blockIdx.x * 64;

  // zero the log-det region (B floats) - blocks 0..31 cover 32768
  if (blockIdx.x < 32) ld_out[blockIdx.x * 1024 + t] = 0.f;

  // stage x tile: one float4 per thread, coalesced
  {
    const int rr = t >> 4, c4 = (t & 15) * 4;
    const float4 v =
        *reinterpret_cast<const float4*>(x + (size_t)b0 * 64 + (size_t)t * 4);
    xs[rr][c4 + 0] = v.x; xs[rr][c4 + 1] = v.y;
    xs[rr][c4 + 2] = v.z; xs[rr][c4 + 3] = v.w;
  }
  __syncthreads();

  const int r  = t & 63;                                  // lane = row
  const int wv = __builtin_amdgcn_readfirstlane(t >> 6);  // wave 0..15

  // ---- layer 1: h1[r][i], i in [wv*4, wv*4+4) ----
  // mask m1[i][d] = (d < (i%63)+1)
  {
    float acc1[4];
    #pragma unroll
    for (int ii = 0; ii < 4; ++ii) acc1[ii] = b1[wv * 4 + ii];
    #pragma unroll 4
    for (int dd = 0; dd < 64; ++dd) {
      const float xv = xs[r][dd];
      #pragma unroll
      for (int ii = 0; ii < 4; ++ii) {
        const int i = wv * 4 + ii;
        const int deg = (i % 63) + 1;                       // uniform
        const float w = (dd < deg) ? W1[i * 64 + dd] : 0.f; // scalar select
        acc1[ii] = fmaf(xv, w, acc1[ii]);
      }
    }
    #pragma unroll
    for (int ii = 0; ii < 4; ++ii) h1s[r][wv * 4 + ii] = fmaxf(acc1[ii], 0.f);
  }
  __syncthreads();   // all xs reads complete here -> xs reusable as h2s

  // ---- layer 2: h2[r][j], j in [wv*2, wv*2+2) ----
  // mask m2[j][i] = (i <= j) || (i == 63)
  {
    float* h2s = &xs[0][0];   // overlay: h2s[row*33 + j]
    float acc2[2];
    #pragma unroll
    for (int jj = 0; jj < 2; ++jj) acc2[jj] = b2[wv * 2 + jj];
    #pragma unroll 4
    for (int i2 = 0; i2 < 64; ++i2) {
      const float hv = h1s[r][i2];
      #pragma unroll
      for (int jj = 0; jj < 2; ++jj) {
        const int j = wv * 2 + jj;
        const bool on = (i2 <= j) || (i2 == 63);            // uniform
        const float w = on ? W2[j * 64 + i2] : 0.f;         // scalar select
        acc2[jj] = fmaf(hv, w, acc2[jj]);
      }
    }
    #pragma unroll
    for (int jj = 0; jj < 2; ++jj)
      h2s[r * 33 + wv * 2 + jj] = fmaxf(acc2[jj], 0.f);
  }
  __syncthreads();

  // coalesced h2 store: threads 0..511, one float4 each
  if (t < 512) {
    const float* h2s = &xs[0][0];
    const int row = t >> 3, c4 = (t & 7) * 4;
    const float4 v = make_float4(h2s[row * 33 + c4 + 0], h2s[row * 33 + c4 + 1],
                                 h2s[row * 33 + c4 + 2], h2s[row * 33 + c4 + 3]);
    *reinterpret_cast<float4*>(h2out + (size_t)b0 * 32 + (size_t)t * 4) = v;
  }
}

// ---------------------------------------------------------------------------
// Kernel B: layer 3 + RQ spline. Grid = (B/64) * 4 d-slices -> 2048 blocks.
// 256 threads (4 waves), lane = row, 4 d's per thread (16 d's per block).
// No launch_bounds squeeze: needs ~68 VGPR (h2r[32] + spline temps).
// LDS 17.6 KB -> 7+ blocks/CU at the VGPR-implied 7 waves/EU.
// ---------------------------------------------------------------------------
__global__ __launch_bounds__(256) void spline_kernel(
    const float* __restrict__ x, const float* __restrict__ h2in,
    const float* __restrict__ W3, const float* __restrict__ b3,
    float* __restrict__ out, int B) {
  __shared__ float h2s[64][33];
  __shared__ float xsl[64][17];   // this block's 16 x-columns
  __shared__ float zsl[64][17];   // z staging for coalesced store
  __shared__ float ldp[4][64];

  const int t = threadIdx.x;
  const int rb = blockIdx.x >> 2;       // row-block
  const int ds = blockIdx.x & 3;        // d-slice: columns [ds*16, ds*16+16)
  const int b0 = rb * 64;

  // stage h2 tile: 64 rows x 32 cols = 512 float4 reads, coalesced
  #pragma unroll
  for (int u = 0; u < 2; ++u) {
    const int idx = t + u * 256;
    const int row = idx >> 3, c4 = (idx & 7) * 4;
    const float4 v = *reinterpret_cast<const float4*>(
        h2in + (size_t)b0 * 32 + (size_t)idx * 4);
    h2s[row][c4 + 0] = v.x; h2s[row][c4 + 1] = v.y;
    h2s[row][c4 + 2] = v.z; h2s[row][c4 + 3] = v.w;
  }
  // stage x slice: row = t>>2, 4 float4-chunks per row
  {
    const int row = t >> 2, c4 = (t & 3) * 4;
    const float4 v = *reinterpret_cast<const float4*>(
        x + ((size_t)(b0 + row) * 64) + ds * 16 + c4);
    xsl[row][c4 + 0] = v.x; xsl[row][c4 + 1] = v.y;
    xsl[row][c4 + 2] = v.z; xsl[row][c4 + 3] = v.w;
  }
  __syncthreads();

  const int r  = t & 63;                                  // lane = row
  const int wv = __builtin_amdgcn_readfirstlane(t >> 6);  // wave 0..3

  float h2r[32];
  #pragma unroll
  for (int k = 0; k < 32; ++k) h2r[k] = h2s[r][k];

  float ldacc = 0.f;

  // ---- layer 3 + spline: 4 d's per thread ----
  // mask m3[(m,d)][k] = (k < d)
  #pragma unroll 1
  for (int di = 0; di < 4; ++di) {
    const int dloc = wv * 4 + di;                          // 0..15, uniform
    const int dU = __builtin_amdgcn_readfirstlane(ds * 16 + dloc);

    float p[NM];
    #pragma unroll
    for (int m = 0; m < NM; ++m) {
      float acc = b3[m * 64 + dU];
      const float* wrow = W3 + (size_t)(m * 64 + dU) * 32;
      #pragma unroll
      for (int kk = 0; kk < 32; ++kk) {
        const float w = (kk < dU) ? wrow[kk] : 0.f;        // scalar select
        acc = fmaf(h2r[kk], w, acc);
      }
      p[m] = acc;
    }

    const float xv = xsl[r][dloc];
    const float xc = fminf(fmaxf(xv, -3.f), 3.f);

    // softmax over widths logits p[0..7]
    float mw = p[0];
    #pragma unroll
    for (int k = 1; k < 8; ++k) mw = fmaxf(mw, p[k]);
    float ew[8], sw = 0.f;
    #pragma unroll
    for (int k = 0; k < 8; ++k) { ew[k] = __expf(p[k] - mw); sw += ew[k]; }
    const float invw = 1.f / sw;

    // softmax over heights logits p[8..15]
    float mh = p[8];
    #pragma unroll
    for (int k = 1; k < 8; ++k) mh = fmaxf(mh, p[8 + k]);
    float eh[8], sh = 0.f;
    #pragma unroll
    for (int k = 0; k < 8; ++k) { eh[k] = __expf(p[8 + k] - mh); sh += eh[k]; }
    const float invh = 1.f / sh;

    const float WSC = 1.0f - 1e-3f * 8.0f;   // 1 - MIN_BIN_WIDTH*K
    float cumw[9], cumh[9];
    cumw[0] = -3.f; cumh[0] = -3.f;
    float cw = 0.f, ch = 0.f;
    #pragma unroll
    for (int k = 0; k < 7; ++k) {
      cw += 1e-3f + WSC * (ew[k] * invw);
      ch += 1e-3f + WSC * (eh[k] * invh);
      cumw[k + 1] = fmaf(6.f, cw, -3.f);
      cumh[k + 1] = fmaf(6.f, ch, -3.f);
    }
    cumw[8] = 3.f; cumh[8] = 3.f;

    float derivs[9];
    derivs[0] = 1.f; derivs[8] = 1.f;
    #pragma unroll
    for (int k = 0; k < 7; ++k) derivs[k + 1] = 1e-3f + softplus_f(p[16 + k]);

    // bin select: idx = sum(xc >= cumw[k]+EPS) - 1, clipped to [0,7]
    float xk = cumw[0], xk1 = cumw[1];
    float yk = cumh[0], yk1 = cumh[1];
    float dk = derivs[0], dk1 = derivs[1];
    #pragma unroll
    for (int k = 1; k < 8; ++k) {
      const bool s = xc >= cumw[k] + 1e-6f;
      xk  = s ? cumw[k]       : xk;
      xk1 = s ? cumw[k + 1]   : xk1;
      yk  = s ? cumh[k]       : yk;
      yk1 = s ? cumh[k + 1]   : yk1;
      dk  = s ? derivs[k]     : dk;
      dk1 = s ? derivs[k + 1] : dk1;
    }

    const float wk = xk1 - xk, hk = yk1 - yk;
    const float invwk = 1.f / wk;
    const float delta = hk * invwk;
    const float theta = (xc - xk) * invwk;
    const float omt = 1.f - theta;
    const float tt = theta * omt;
    const float th2 = theta * theta;
    const float num = hk * (delta * th2 + dk * tt);
    const float den = delta + (dk + dk1 - 2.f * delta) * tt;
    const float yv = yk + num / den;
    const float dnum = delta * delta * (dk1 * th2 + 2.f * delta * tt + dk * omt * omt);
    const float ldv = __logf(dnum) - 2.f * __logf(den);

    const bool inside = (xv >= -3.f) && (xv <= 3.f);
    zsl[r][dloc] = inside ? yv : xv;
    ldacc += inside ? ldv : 0.f;
  }

  ldp[wv][r] = ldacc;
  __syncthreads();

  // coalesced z write: row = t>>2, 4 float4-chunks per row
  {
    const int row = t >> 2, c4 = (t & 3) * 4;
    const float4 v = make_float4(zsl[row][c4 + 0], zsl[row][c4 + 1],
                                 zsl[row][c4 + 2], zsl[row][c4 + 3]);
    *reinterpret_cast<float4*>(
        out + ((size_t)(b0 + row) * 64) + ds * 16 + c4) = v;
  }
  // log-det partial: one atomicAdd per row per d-slice (4 per row total)
  if (t < 64) {
    const float s = ldp[0][t] + ldp[1][t] + ldp[2][t] + ldp[3][t];
    atomicAdd(&out[(size_t)B * 64 + b0 + t], s);
  }
}

extern "C" void kernel_launch(void* const* d_in, const int* in_sizes, int n_in,
                              void* d_out, int out_size, void* d_ws, size_t ws_size,
                              hipStream_t stream) {
  const float* x  = (const float*)d_in[0];
  const float* W1 = (const float*)d_in[1];
  const float* b1 = (const float*)d_in[2];
  const float* W2 = (const float*)d_in[3];
  const float* b2 = (const float*)d_in[4];
  const float* W3 = (const float*)d_in[5];
  const float* b3 = (const float*)d_in[6];
  float* out = (float*)d_out;
  float* h2ws = (float*)d_ws;           // B*32 floats = 4 MB

  const int B = in_sizes[0] / 64;       // 32768

  h2_kernel<<<B / 64, 1024, 0, stream>>>(
      x, W1, b1, W2, b2, h2ws, out + (size_t)B * 64, B);

  spline_kernel<<<(B / 64) * 4, 256, 0, stream>>>(
      x, h2ws, W3, b3, out, B);
}

// Round 5
// 155.886 us; speedup vs baseline: 2.6654x; 2.6654x over previous
//
#include <hip/hip_runtime.h>

#define NM 23        // 3*K - 1, K = 8

__device__ __forceinline__ float softplus_f(float v) {
  // stable: max(v,0) + log(1 + exp(-|v|))
  return fmaxf(v, 0.f) + __logf(1.f + __expf(-fabsf(v)));
}

// ---------------------------------------------------------------------------
// Prep: apply MADE masks + transpose weights into workspace; zero ld region.
//   W1t[d][i]    = W1[i][d] * m1[i][d]          (4096 floats)
//   W2t[i][j]    = W2[j][i] * m2[j][i]          (2048 floats)
//   W3t[d][m][k] = W3[m*64+d][k] * (k<d)        (47104 floats)
//   b3t[d][m]    = b3[m*64+d]                   (1472 floats)
// Pre-masking matters: inner loops become pure v_fmac with uniform s_load
// operands. Inline ?: masking costs ~2.6x VALU bloat (measured round 3).
// GRID MUST COVER 47104 W3t ELEMENTS (round-4 bug: 32768-thread grid left
// W3t[d>=44] as 0xAA poison -> absmax 0.24 fail).
// ---------------------------------------------------------------------------
__global__ __launch_bounds__(256) void prep_kernel(
    const float* __restrict__ W1, const float* __restrict__ W2,
    const float* __restrict__ W3, const float* __restrict__ b3,
    float* __restrict__ W1t, float* __restrict__ W2t,
    float* __restrict__ W3t, float* __restrict__ b3t,
    float* __restrict__ ld_out, int B) {
  int idx = blockIdx.x * 256 + threadIdx.x;
  if (idx < B) ld_out[idx] = 0.f;             // zero log-det accumulators
  if (idx < 64 * 64) {                        // W1t[d][i]
    int d = idx >> 6, i = idx & 63;
    int deg = (i % 63) + 1;
    W1t[idx] = (d < deg) ? W1[i * 64 + d] : 0.f;
  }
  if (idx < 64 * 32) {                        // W2t[i][j]
    int i = idx >> 5, j = idx & 31;
    int hdeg = (i % 63) + 1;
    W2t[idx] = (hdeg <= j + 1) ? W2[j * 64 + i] : 0.f;
  }
  if (idx < 64 * NM * 32) {                   // W3t[d][m][k]
    int d = idx / (NM * 32);
    int rem = idx - d * (NM * 32);
    int m = rem >> 5, k = rem & 31;
    W3t[idx] = (k < d) ? W3[(m * 64 + d) * 32 + k] : 0.f;
  }
  if (idx < 64 * NM) {                        // b3t[d][m]
    int d = idx / NM, m = idx - d * NM;
    b3t[idx] = b3[m * 64 + d];
  }
}

// ---------------------------------------------------------------------------
// Kernel A: layers 1+2, 64 rows/block, 1024 threads (16 waves), lane = row.
// Pre-masked weights -> pure fmac; tiny register footprint.
// ---------------------------------------------------------------------------
__global__ __launch_bounds__(1024, 4) void h2_kernel(
    const float* __restrict__ x,
    const float* __restrict__ W1t, const float* __restrict__ b1,
    const float* __restrict__ W2t, const float* __restrict__ b2,
    float* __restrict__ h2out) {
  __shared__ float xs[64][65];     // overlaid by h2s[64][33] after layer 2
  __shared__ float h1s[64][65];

  const int t = threadIdx.x;
  const int b0 = blockIdx.x * 64;

  // stage x tile: one float4 per thread, coalesced
  {
    const int rr = t >> 4, c4 = (t & 15) * 4;
    const float4 v =
        *reinterpret_cast<const float4*>(x + (size_t)b0 * 64 + (size_t)t * 4);
    xs[rr][c4 + 0] = v.x; xs[rr][c4 + 1] = v.y;
    xs[rr][c4 + 2] = v.z; xs[rr][c4 + 3] = v.w;
  }
  __syncthreads();

  const int r  = t & 63;                                  // lane = row
  const int wv = __builtin_amdgcn_readfirstlane(t >> 6);  // wave 0..15

  // ---- layer 1: h1[r][i], i in [wv*4, wv*4+4) ----
  {
    const int iBase = wv * 4;
    float acc1[4];
    #pragma unroll
    for (int ii = 0; ii < 4; ++ii) acc1[ii] = b1[iBase + ii];
    #pragma unroll 8
    for (int dd = 0; dd < 64; ++dd) {
      const float xv = xs[r][dd];
      const float* wrow = W1t + dd * 64 + iBase;          // uniform dwordx4
      #pragma unroll
      for (int ii = 0; ii < 4; ++ii) acc1[ii] = fmaf(xv, wrow[ii], acc1[ii]);
    }
    #pragma unroll
    for (int ii = 0; ii < 4; ++ii) h1s[r][iBase + ii] = fmaxf(acc1[ii], 0.f);
  }
  __syncthreads();   // all xs reads done -> xs reusable as h2s

  // ---- layer 2: h2[r][j], j in [wv*2, wv*2+2) ----
  {
    float* h2s = &xs[0][0];   // overlay: h2s[row*33 + j]
    const int jBase = wv * 2;
    float acc2[2];
    #pragma unroll
    for (int jj = 0; jj < 2; ++jj) acc2[jj] = b2[jBase + jj];
    #pragma unroll 8
    for (int i2 = 0; i2 < 64; ++i2) {
      const float hv = h1s[r][i2];
      const float* wrow = W2t + i2 * 32 + jBase;          // uniform dwordx2
      #pragma unroll
      for (int jj = 0; jj < 2; ++jj) acc2[jj] = fmaf(hv, wrow[jj], acc2[jj]);
    }
    #pragma unroll
    for (int jj = 0; jj < 2; ++jj)
      h2s[r * 33 + jBase + jj] = fmaxf(acc2[jj], 0.f);
  }
  __syncthreads();

  // coalesced h2 store: threads 0..511, one float4 each
  if (t < 512) {
    const float* h2s = &xs[0][0];
    const int row = t >> 3, c4 = (t & 7) * 4;
    const float4 v = make_float4(h2s[row * 33 + c4 + 0], h2s[row * 33 + c4 + 1],
                                 h2s[row * 33 + c4 + 2], h2s[row * 33 + c4 + 3]);
    *reinterpret_cast<float4*>(h2out + (size_t)b0 * 32 + (size_t)t * 4) = v;
  }
}

// ---------------------------------------------------------------------------
// Kernel B: layer 3 + RQ spline. Grid = (B/64) * 4 d-slices = 2048 blocks.
// 256 threads (4 waves), lane = row, 4 d's/thread (16 d's per block).
// Pre-masked W3t[d][m][k]: contiguous 2944 B per d -> s_load_dwordx16 stream,
// inner loop pure v_fmac. Natural ~68 VGPR -> 7 waves/SIMD (~87% occ cap).
// ---------------------------------------------------------------------------
__global__ __launch_bounds__(256) void spline_kernel(
    const float* __restrict__ x, const float* __restrict__ h2in,
    const float* __restrict__ W3t, const float* __restrict__ b3t,
    float* __restrict__ out, int B) {
  __shared__ float h2s[64][33];
  __shared__ float xz[64][17];    // x slice in, z staging out (same owner/elem)
  __shared__ float ldp[4][64];

  const int t = threadIdx.x;
  const int rb = blockIdx.x >> 2;       // row-block
  const int ds = blockIdx.x & 3;        // d-slice: columns [ds*16, ds*16+16)
  const int b0 = rb * 64;

  // stage h2 tile: 64 rows x 32 cols, coalesced float4
  #pragma unroll
  for (int u = 0; u < 2; ++u) {
    const int idx = t + u * 256;
    const int row = idx >> 3, c4 = (idx & 7) * 4;
    const float4 v = *reinterpret_cast<const float4*>(
        h2in + (size_t)b0 * 32 + (size_t)idx * 4);
    h2s[row][c4 + 0] = v.x; h2s[row][c4 + 1] = v.y;
    h2s[row][c4 + 2] = v.z; h2s[row][c4 + 3] = v.w;
  }
  // stage x slice: 64 rows x 16 cols, coalesced float4
  {
    const int row = t >> 2, c4 = (t & 3) * 4;
    const float4 v = *reinterpret_cast<const float4*>(
        x + ((size_t)(b0 + row) * 64) + ds * 16 + c4);
    xz[row][c4 + 0] = v.x; xz[row][c4 + 1] = v.y;
    xz[row][c4 + 2] = v.z; xz[row][c4 + 3] = v.w;
  }
  __syncthreads();

  const int r  = t & 63;                                  // lane = row
  const int wv = __builtin_amdgcn_readfirstlane(t >> 6);  // wave 0..3

  float h2r[32];
  #pragma unroll
  for (int k = 0; k < 32; ++k) h2r[k] = h2s[r][k];

  float ldacc = 0.f;

  // ---- layer 3 + spline: 4 d's per thread ----
  #pragma unroll 1
  for (int di = 0; di < 4; ++di) {
    const int dloc = wv * 4 + di;                          // 0..15, uniform
    const int dU = __builtin_amdgcn_readfirstlane(ds * 16 + dloc);
    const float* w3d = W3t + (size_t)dU * (NM * 32);
    const float* b3d = b3t + dU * NM;

    float p[NM];
    #pragma unroll
    for (int m = 0; m < NM; ++m) {
      float acc = b3d[m];
      const float* wrow = w3d + m * 32;
      #pragma unroll
      for (int kk = 0; kk < 32; ++kk) acc = fmaf(h2r[kk], wrow[kk], acc);
      p[m] = acc;
    }

    const float xv = xz[r][dloc];
    const float xc = fminf(fmaxf(xv, -3.f), 3.f);

    // softmax over widths logits p[0..7]
    float mw = p[0];
    #pragma unroll
    for (int k = 1; k < 8; ++k) mw = fmaxf(mw, p[k]);
    float ew[8], sw = 0.f;
    #pragma unroll
    for (int k = 0; k < 8; ++k) { ew[k] = __expf(p[k] - mw); sw += ew[k]; }
    const float invw = 1.f / sw;

    // softmax over heights logits p[8..15]
    float mh = p[8];
    #pragma unroll
    for (int k = 1; k < 8; ++k) mh = fmaxf(mh, p[8 + k]);
    float eh[8], sh = 0.f;
    #pragma unroll
    for (int k = 0; k < 8; ++k) { eh[k] = __expf(p[8 + k] - mh); sh += eh[k]; }
    const float invh = 1.f / sh;

    const float WSC = 1.0f - 1e-3f * 8.0f;   // 1 - MIN_BIN_WIDTH*K
    float cumw[9], cumh[9];
    cumw[0] = -3.f; cumh[0] = -3.f;
    float cw = 0.f, ch = 0.f;
    #pragma unroll
    for (int k = 0; k < 7; ++k) {
      cw += 1e-3f + WSC * (ew[k] * invw);
      ch += 1e-3f + WSC * (eh[k] * invh);
      cumw[k + 1] = fmaf(6.f, cw, -3.f);
      cumh[k + 1] = fmaf(6.f, ch, -3.f);
    }
    cumw[8] = 3.f; cumh[8] = 3.f;

    float derivs[9];
    derivs[0] = 1.f; derivs[8] = 1.f;
    #pragma unroll
    for (int k = 0; k < 7; ++k) derivs[k + 1] = 1e-3f + softplus_f(p[16 + k]);

    // bin select: idx = sum(xc >= cumw[k]+EPS) - 1, clipped to [0,7]
    float xk = cumw[0], xk1 = cumw[1];
    float yk = cumh[0], yk1 = cumh[1];
    float dk = derivs[0], dk1 = derivs[1];
    #pragma unroll
    for (int k = 1; k < 8; ++k) {
      const bool s = xc >= cumw[k] + 1e-6f;
      xk  = s ? cumw[k]       : xk;
      xk1 = s ? cumw[k + 1]   : xk1;
      yk  = s ? cumh[k]       : yk;
      yk1 = s ? cumh[k + 1]   : yk1;
      dk  = s ? derivs[k]     : dk;
      dk1 = s ? derivs[k + 1] : dk1;
    }

    const float wk = xk1 - xk, hk = yk1 - yk;
    const float invwk = 1.f / wk;
    const float delta = hk * invwk;
    const float theta = (xc - xk) * invwk;
    const float omt = 1.f - theta;
    const float tt = theta * omt;
    const float th2 = theta * theta;
    const float num = hk * (delta * th2 + dk * tt);
    const float den = delta + (dk + dk1 - 2.f * delta) * tt;
    const float yv = yk + num / den;
    const float dnum = delta * delta * (dk1 * th2 + 2.f * delta * tt + dk * omt * omt);
    const float ldv = __logf(dnum) - 2.f * __logf(den);

    const bool inside = (xv >= -3.f) && (xv <= 3.f);
    xz[r][dloc] = inside ? yv : xv;          // overlay: z replaces x (same owner)
    ldacc += inside ? ldv : 0.f;
  }

  ldp[wv][r] = ldacc;
  __syncthreads();

  // coalesced z write
  {
    const int row = t >> 2, c4 = (t & 3) * 4;
    const float4 v = make_float4(xz[row][c4 + 0], xz[row][c4 + 1],
                                 xz[row][c4 + 2], xz[row][c4 + 3]);
    *reinterpret_cast<float4*>(
        out + ((size_t)(b0 + row) * 64) + ds * 16 + c4) = v;
  }
  // log-det partial: one atomicAdd per row per d-slice
  if (t < 64) {
    const float s = ldp[0][t] + ldp[1][t] + ldp[2][t] + ldp[3][t];
    atomicAdd(&out[(size_t)B * 64 + b0 + t], s);
  }
}

extern "C" void kernel_launch(void* const* d_in, const int* in_sizes, int n_in,
                              void* d_out, int out_size, void* d_ws, size_t ws_size,
                              hipStream_t stream) {
  const float* x  = (const float*)d_in[0];
  const float* W1 = (const float*)d_in[1];
  const float* b1 = (const float*)d_in[2];
  const float* W2 = (const float*)d_in[3];
  const float* b2 = (const float*)d_in[4];
  const float* W3 = (const float*)d_in[5];
  const float* b3 = (const float*)d_in[6];
  float* out = (float*)d_out;
  float* ws  = (float*)d_ws;

  float* W1t = ws;                       // 4096
  float* W2t = ws + 4096;                // 2048
  float* W3t = ws + 6144;                // 47104
  float* b3t = ws + 53248;               // 1472
  float* h2w = ws + 55296;               // B*32 floats

  const int B = in_sizes[0] / 64;        // 32768

  // grid must cover max(B, 64*NM*32=47104) elements
  const int prep_n = (B > 64 * NM * 32) ? B : 64 * NM * 32;
  prep_kernel<<<(prep_n + 255) / 256, 256, 0, stream>>>(
      W1, W2, W3, b3, W1t, W2t, W3t, b3t, out + (size_t)B * 64, B);

  h2_kernel<<<B / 64, 1024, 0, stream>>>(x, W1t, b1, W2t, b2, h2w);

  spline_kernel<<<(B / 64) * 4, 256, 0, stream>>>(
      x, h2w, W3t, b3t, out, B);
}